// Round 2
// baseline (845.293 us; speedup 1.0000x reference)
//
#include <hip/hip_runtime.h>
#include <hip/hip_bf16.h>

// Problem constants
#define BATCH 2
#define SLEN 2048
#define DMODEL 1024
#define NHEADS 16
#define NKV 4
#define DHEAD 64
#define WINDOW 256
#define NGLOBAL 4

typedef __attribute__((ext_vector_type(8))) short short8;
typedef __attribute__((ext_vector_type(4))) float floatx4;

__device__ inline ushort f2bf(float f) {
    __hip_bfloat16 h = __float2bfloat16(f);
    return *reinterpret_cast<ushort*>(&h);
}
// dtype flag: cos[0]==1.0f exactly. fp32 -> low16 of first dword == 0x0000;
// bf16 pair -> low16 == 0x3F80. Wave-uniform branch, graph-capture safe.
__device__ inline bool is_bf16_inputs(const uint* cosu) {
    return (cosu[0] & 0xFFFFu) != 0u;
}

// ---------------- canonicalize: any (f32|bf16) -> bf16, vectorized x8 ----------------
__global__ __launch_bounds__(256) void cvt_to_bf16(const void* __restrict__ in,
                                                   ushort* __restrict__ out,
                                                   const uint* __restrict__ cosu,
                                                   size_t n8)
{
    bool isbf = is_bf16_inputs(cosu);
    size_t i = (size_t)blockIdx.x * 256 + threadIdx.x;
    if (i >= n8) return;
    size_t e = i * 8;
    if (isbf) {
        *reinterpret_cast<uint4*>(out + e) = reinterpret_cast<const uint4*>(in)[i];
    } else {
        const float* f = reinterpret_cast<const float*>(in) + e;
        ushort o[8];
#pragma unroll
        for (int j = 0; j < 8; ++j) o[j] = f2bf(f[j]);
        *reinterpret_cast<uint4*>(out + e) = *reinterpret_cast<uint4*>(o);
    }
}

// ---------------- canonicalize: any (f32|bf16) -> f32 ----------------
__global__ __launch_bounds__(256) void cvt_to_f32(const void* __restrict__ in,
                                                  float* __restrict__ out,
                                                  const uint* __restrict__ cosu,
                                                  int n)
{
    bool isbf = is_bf16_inputs(cosu);
    int i = blockIdx.x * 256 + threadIdx.x;
    if (i >= n) return;
    out[i] = isbf ? __bfloat162float(reinterpret_cast<const __hip_bfloat16*>(in)[i])
                  : reinterpret_cast<const float*>(in)[i];
}

// ---------------- transpose any (R x C) -> bf16 (C x R) ----------------
__global__ __launch_bounds__(256) void transpose_to_bf16(const void* __restrict__ in,
                                                         ushort* __restrict__ out,
                                                         int R, int C,
                                                         const uint* __restrict__ cosu)
{
    bool isbf = is_bf16_inputs(cosu);
    __shared__ ushort t[32][33];
    int bx = blockIdx.x * 32;   // col tile of in
    int by = blockIdx.y * 32;   // row tile of in
    int tx = threadIdx.x & 31, ty = threadIdx.x >> 5;  // 32x8
#pragma unroll
    for (int j = 0; j < 32; j += 8) {
        size_t idx = (size_t)(by + ty + j) * C + bx + tx;
        ushort v;
        if (isbf) v = reinterpret_cast<const ushort*>(in)[idx];
        else      v = f2bf(reinterpret_cast<const float*>(in)[idx]);
        t[ty + j][tx] = v;
    }
    __syncthreads();
#pragma unroll
    for (int j = 0; j < 32; j += 8)
        out[(size_t)(bx + ty + j) * R + by + tx] = t[tx][ty + j];
}

// ---------------- MFMA GEMM: C[M,N] = A[M,K] (bf16) x Bt[N,K]^T (bf16) ----------------
// 64x64 tile, BK=64, 4 waves 2x2, each wave 32x32 via 2x2 mfma_f32_16x16x32_bf16.
// A-frag: A[m=lane&15][k=quad*8+j]; B-frag: B[k=quad*8+j][n=lane&15] = Bt[n][k];
// C/D: row=quad*4+reg, col=lane&15.
// OUT_MODE: 0 = f32 store, 1 = dynamic (bf16 if inputs bf16, else f32).
template<int OUT_MODE>
__global__ __launch_bounds__(256) void gemm_bt(const ushort* __restrict__ A,
                                               const ushort* __restrict__ Bt,
                                               void* __restrict__ Cp,
                                               int M, int N, int K,
                                               const uint* __restrict__ cosu)
{
    __shared__ ushort lsA[64 * 72];
    __shared__ ushort lsB[64 * 72];
    const int tid = threadIdx.x;
    const int lane = tid & 63;
    const int wid = tid >> 6;
    const int wm = wid >> 1, wn = wid & 1;
    const int ln15 = lane & 15, quad = lane >> 4;
    const int rm = blockIdx.y * 64, cn = blockIdx.x * 64;

    const int srow = tid >> 2;        // 0..63
    const int sc8 = (tid & 3) * 2;    // chunk pairs: 0,2,4,6

    floatx4 acc00 = {0,0,0,0}, acc01 = {0,0,0,0}, acc10 = {0,0,0,0}, acc11 = {0,0,0,0};

    for (int k0 = 0; k0 < K; k0 += 64) {
        __syncthreads();
        const uint4* ga = reinterpret_cast<const uint4*>(&A[(size_t)(rm + srow) * K + k0 + sc8 * 8]);
        uint4 va0 = ga[0], va1 = ga[1];
        const uint4* gb = reinterpret_cast<const uint4*>(&Bt[(size_t)(cn + srow) * K + k0 + sc8 * 8]);
        uint4 vb0 = gb[0], vb1 = gb[1];
        *reinterpret_cast<uint4*>(&lsA[srow * 72 + sc8 * 8]) = va0;
        *reinterpret_cast<uint4*>(&lsA[srow * 72 + sc8 * 8 + 8]) = va1;
        *reinterpret_cast<uint4*>(&lsB[srow * 72 + sc8 * 8]) = vb0;
        *reinterpret_cast<uint4*>(&lsB[srow * 72 + sc8 * 8 + 8]) = vb1;
        __syncthreads();
#pragma unroll
        for (int kk = 0; kk < 64; kk += 32) {
            short8 a0 = *reinterpret_cast<const short8*>(&lsA[(wm * 32 + ln15) * 72 + kk + quad * 8]);
            short8 a1 = *reinterpret_cast<const short8*>(&lsA[(wm * 32 + 16 + ln15) * 72 + kk + quad * 8]);
            short8 b0 = *reinterpret_cast<const short8*>(&lsB[(wn * 32 + ln15) * 72 + kk + quad * 8]);
            short8 b1 = *reinterpret_cast<const short8*>(&lsB[(wn * 32 + 16 + ln15) * 72 + kk + quad * 8]);
            acc00 = __builtin_amdgcn_mfma_f32_16x16x32_bf16(a0, b0, acc00, 0, 0, 0);
            acc01 = __builtin_amdgcn_mfma_f32_16x16x32_bf16(a0, b1, acc01, 0, 0, 0);
            acc10 = __builtin_amdgcn_mfma_f32_16x16x32_bf16(a1, b0, acc10, 0, 0, 0);
            acc11 = __builtin_amdgcn_mfma_f32_16x16x32_bf16(a1, b1, acc11, 0, 0, 0);
        }
    }

    bool outbf = (OUT_MODE == 1) ? is_bf16_inputs(cosu) : false;
#pragma unroll
    for (int mi = 0; mi < 2; ++mi) {
        floatx4 r0 = mi ? acc10 : acc00;
        floatx4 r1 = mi ? acc11 : acc01;
#pragma unroll
        for (int r = 0; r < 4; ++r) {
            int grow = rm + wm * 32 + mi * 16 + quad * 4 + r;
            int gc0 = cn + wn * 32 + ln15;
            if (OUT_MODE == 1 && outbf) {
                ushort* C = reinterpret_cast<ushort*>(Cp);
                C[(size_t)grow * N + gc0] = f2bf(r0[r]);
                C[(size_t)grow * N + gc0 + 16] = f2bf(r1[r]);
            } else {
                float* C = reinterpret_cast<float*>(Cp);
                C[(size_t)grow * N + gc0] = r0[r];
                C[(size_t)grow * N + gc0 + 16] = r1[r];
            }
        }
    }
}

// ---------------- L2 normalize + RoPE + layout shuffle ----------------
// qkv: fp32 [4096][1536] (Q cols 0..1023, K 1024..1279, V 1280..1535)
// Qn: fp32 [(b*16+h)*2048 + s][64]
// Kt: fp32 [((b*4+hkv)*64 + d)*2048 + s]
// Vn: fp32 [((b*4+hkv)*2048 + s)*64 + d]
__global__ __launch_bounds__(64) void norm_rope(const float* __restrict__ qkv,
                                                const float* __restrict__ cosf,
                                                const float* __restrict__ sinf,
                                                float* __restrict__ Qn,
                                                float* __restrict__ Kt,
                                                float* __restrict__ Vn)
{
    int lane = threadIdx.x;            // 0..63 = head dim
    int hh = blockIdx.x % 24;          // 0..15 q heads, 16..19 k heads, 20..23 v heads
    int s = (blockIdx.x / 24) & (SLEN - 1);
    int b = blockIdx.x / (24 * SLEN);
    size_t row = (size_t)(b * SLEN + s) * 1536;

    if (hh >= 20) {
        int hkv = hh - 20;
        float v = qkv[row + 1280 + hkv * 64 + lane];
        Vn[((size_t)((b * NKV + hkv) * SLEN + s)) * 64 + lane] = v;
        return;
    }
    bool isq = hh < 16;
    int col = isq ? hh * 64 : 1024 + (hh - 16) * 64;
    float v = qkv[row + col + lane];
    float ss = v * v;
#pragma unroll
    for (int off = 32; off; off >>= 1) ss += __shfl_xor(ss, off, 64);
    float nv = v / (sqrtf(ss) + 1e-8f);
    float p = __shfl(nv, lane ^ 32, 64);
    int dh = lane & 31;
    float c = cosf[s * 32 + dh];
    float sn = sinf[s * 32 + dh];
    float o = (lane < 32) ? (nv * c - p * sn) : (p * sn + nv * c);
    if (isq) {
        Qn[((size_t)((b * NHEADS + hh) * SLEN + s)) * 64 + lane] = o;
    } else {
        int hkv = hh - 16;
        Kt[((size_t)((b * NKV + hkv) * 64 + lane)) * SLEN + s] = o;
    }
}

// ---------------- windowed attention: one wave per query ----------------
__global__ __launch_bounds__(256) void attn(const float* __restrict__ Qn,
                                            const float* __restrict__ Kt,
                                            const float* __restrict__ Vn,
                                            ushort* __restrict__ ctx)
{
    int lane = threadIdx.x & 63;
    int gid = blockIdx.x * 4 + (threadIdx.x >> 6);  // (b*16+h)*2048 + s
    int s = gid & (SLEN - 1);
    int bh = gid >> 11;
    int h = bh & (NHEADS - 1);
    int b = bh >> 4;
    int hkv = h >> 2;

    float qv = Qn[(size_t)gid * 64 + lane];

    int start = s - (WINDOW - 1); if (start < 0) start = 0;
    int nwin = s - start + 1;                  // 1..256
    int nblk = (nwin + 63) >> 6;               // 1..4
    int nglob = start < NGLOBAL ? start : NGLOBAL;

    const float* kb = Kt + (size_t)(b * NKV + hkv) * 64 * SLEN;
    float sc0 = 0.f, sc1 = 0.f, sc2 = 0.f, sc3 = 0.f, scg = 0.f;
    for (int d = 0; d < 64; ++d) {
        float qd = __shfl(qv, d, 64);
        const float* r = kb + (size_t)d * SLEN;
        sc0 += qd * r[start + lane];
        if (nblk > 1) sc1 += qd * r[start + 64 + lane];
        if (nblk > 2) sc2 += qd * r[start + 128 + lane];
        if (nblk > 3) sc3 += qd * r[start + 192 + lane];
        if (nglob)    scg += qd * r[lane];
    }

    const float cs = 0.125f / 15.0f;  // ATTN_SCALE / SOFTCAP
    sc0 = (start + lane <= s)       ? 15.f * tanhf(sc0 * cs) : -1e30f;
    sc1 = (start + 64 + lane <= s)  ? 15.f * tanhf(sc1 * cs) : -1e30f;
    sc2 = (start + 128 + lane <= s) ? 15.f * tanhf(sc2 * cs) : -1e30f;
    sc3 = (start + 192 + lane <= s) ? 15.f * tanhf(sc3 * cs) : -1e30f;
    scg = (lane < nglob)            ? 15.f * tanhf(scg * cs) : -1e30f;

    float m = fmaxf(fmaxf(fmaxf(sc0, sc1), fmaxf(sc2, sc3)), scg);
#pragma unroll
    for (int off = 32; off; off >>= 1) m = fmaxf(m, __shfl_xor(m, off, 64));
    float e0 = __expf(sc0 - m), e1 = __expf(sc1 - m), e2 = __expf(sc2 - m),
          e3 = __expf(sc3 - m), eg = __expf(scg - m);
    float l = e0 + e1 + e2 + e3 + eg;
#pragma unroll
    for (int off = 32; off; off >>= 1) l += __shfl_xor(l, off, 64);
    float inv = 1.f / l;
    float w0 = e0 * inv, w1 = e1 * inv, w2 = e2 * inv, w3 = e3 * inv, wg = eg * inv;

    const float* vb = Vn + (size_t)(b * NKV + hkv) * SLEN * 64;
    float out = 0.f;
    {
        const float* vr = vb + (size_t)start * 64 + lane;
        int c0 = nwin < 64 ? nwin : 64;
        for (int i = 0; i < c0; ++i) out += __shfl(w0, i, 64) * vr[(size_t)i * 64];
        if (nblk > 1) {
            int c = nwin - 64; if (c > 64) c = 64;
            const float* v2 = vr + 64 * 64;
            for (int i = 0; i < c; ++i) out += __shfl(w1, i, 64) * v2[(size_t)i * 64];
        }
        if (nblk > 2) {
            int c = nwin - 128; if (c > 64) c = 64;
            const float* v3 = vr + 128 * 64;
            for (int i = 0; i < c; ++i) out += __shfl(w2, i, 64) * v3[(size_t)i * 64];
        }
        if (nblk > 3) {
            int c = nwin - 192; if (c > 64) c = 64;
            const float* v4 = vr + 192 * 64;
            for (int i = 0; i < c; ++i) out += __shfl(w3, i, 64) * v4[(size_t)i * 64];
        }
        for (int i = 0; i < nglob; ++i) out += __shfl(wg, i, 64) * vb[(size_t)i * 64 + lane];
    }
    ctx[((size_t)(b * SLEN + s)) * DMODEL + h * 64 + lane] = f2bf(out);
}

// ---------------- launch ----------------
extern "C" void kernel_launch(void* const* d_in, const int* in_sizes, int n_in,
                              void* d_out, int out_size, void* d_ws, size_t ws_size,
                              hipStream_t stream)
{
    (void)in_sizes; (void)n_in; (void)out_size; (void)ws_size;
    const void* x = d_in[0];
    const void* cosi = d_in[1];
    const void* sini = d_in[2];
    const uint* cosu = (const uint*)d_in[1];   // dtype sentinel: cos[0]==1.0
    // d_in[3] = mask: computed analytically, not read
    const void* Wq = d_in[4];
    const void* Wk = d_in[5];
    const void* Wv = d_in[6];
    const void* Wo = d_in[7];

    // workspace layout (all 16B-aligned offsets)
    ushort* xb = (ushort*)d_ws;                        // [4096][1024] bf16 canonical x
    ushort* Wt = xb + (size_t)4096 * 1024;             // [1536][1024] bf16 (Wq^T|Wk^T|Wv^T)
    ushort* Wot = Wt + (size_t)1536 * 1024;            // [1024][1024] bf16
    float* cosf = (float*)(Wot + (size_t)1024 * 1024); // [2048*32] f32
    float* sinf = cosf + (size_t)SLEN * 32;            // [2048*32] f32
    float* qkv = sinf + (size_t)SLEN * 32;             // [4096][1536] fp32
    float* Qn = qkv + (size_t)4096 * 1536;             // [2*16*2048][64]
    float* Kt = Qn + (size_t)BATCH * NHEADS * SLEN * 64;
    float* Vn = Kt + (size_t)BATCH * NKV * 64 * SLEN;
    ushort* ctx = (ushort*)(Vn + (size_t)BATCH * NKV * SLEN * 64); // [4096][1024] bf16

    // 0) canonicalize inputs (dtype detected on-device from cos[0])
    cvt_to_bf16<<<dim3(2048), 256, 0, stream>>>(x, xb, cosu, (size_t)4096 * 1024 / 8);
    cvt_to_f32<<<dim3(256), 256, 0, stream>>>(cosi, cosf, cosu, SLEN * 32);
    cvt_to_f32<<<dim3(256), 256, 0, stream>>>(sini, sinf, cosu, SLEN * 32);

    // 1) transpose weights to K-major bf16
    transpose_to_bf16<<<dim3(32, 32), 256, 0, stream>>>(Wq, Wt, 1024, 1024, cosu);
    transpose_to_bf16<<<dim3(8, 32), 256, 0, stream>>>(Wk, Wt + (size_t)1024 * 1024, 1024, 256, cosu);
    transpose_to_bf16<<<dim3(8, 32), 256, 0, stream>>>(Wv, Wt + (size_t)1280 * 1024, 1024, 256, cosu);
    transpose_to_bf16<<<dim3(32, 32), 256, 0, stream>>>(Wo, Wot, 1024, 1024, cosu);

    // 2) fused QKV projection: [4096,1024] x [1024,1536] -> f32
    gemm_bt<0><<<dim3(24, 64), 256, 0, stream>>>(xb, Wt, qkv, 4096, 1536, 1024, cosu);

    // 3) l2-normalize + rope + relayout
    norm_rope<<<dim3(BATCH * SLEN * 24), 64, 0, stream>>>(qkv, cosf, sinf, Qn, Kt, Vn);

    // 4) windowed attention
    attn<<<dim3(BATCH * NHEADS * SLEN / 4), 256, 0, stream>>>(Qn, Kt, Vn, ctx);

    // 5) output projection: [4096,1024] x [1024,1024] -> out (dtype-matched)
    gemm_bt<1><<<dim3(16, 64), 256, 0, stream>>>(ctx, Wot, d_out, 4096, 1024, 1024, cosu);
}

// Round 3
// 204.059 us; speedup vs baseline: 4.1424x; 4.1424x over previous
//
#include <hip/hip_runtime.h>
#include <hip/hip_bf16.h>

// Problem constants
#define BATCH 2
#define SLEN 2048
#define DMODEL 1024
#define NHEADS 16
#define NKV 4
#define DHEAD 64
#define WINDOW 256
#define NGLOBAL 4

typedef __attribute__((ext_vector_type(8))) short short8;
typedef __attribute__((ext_vector_type(4))) short shortx4;
typedef __attribute__((ext_vector_type(4))) float floatx4;

__device__ inline ushort f2bf(float f) {
    __hip_bfloat16 h = __float2bfloat16(f);
    return *reinterpret_cast<ushort*>(&h);
}
__device__ inline float bf2f(ushort u) {
    __hip_bfloat16 h = *reinterpret_cast<__hip_bfloat16*>(&u);
    return __bfloat162float(h);
}
// dtype flag: cos[0]==1.0f exactly. fp32 -> low16 of first dword == 0x0000;
// bf16 pair -> low16 == 0x3F80. Wave-uniform branch, graph-capture safe.
__device__ inline bool is_bf16_inputs(const uint* cosu) {
    return (cosu[0] & 0xFFFFu) != 0u;
}

// ---------------- canonicalize: any (f32|bf16) -> bf16, vectorized x8 ----------------
__global__ __launch_bounds__(256) void cvt_to_bf16(const void* __restrict__ in,
                                                   ushort* __restrict__ out,
                                                   const uint* __restrict__ cosu,
                                                   size_t n8)
{
    bool isbf = is_bf16_inputs(cosu);
    size_t i = (size_t)blockIdx.x * 256 + threadIdx.x;
    if (i >= n8) return;
    size_t e = i * 8;
    if (isbf) {
        *reinterpret_cast<uint4*>(out + e) = reinterpret_cast<const uint4*>(in)[i];
    } else {
        const float* f = reinterpret_cast<const float*>(in) + e;
        ushort o[8];
#pragma unroll
        for (int j = 0; j < 8; ++j) o[j] = f2bf(f[j]);
        *reinterpret_cast<uint4*>(out + e) = *reinterpret_cast<uint4*>(o);
    }
}

// ---------------- canonicalize: any (f32|bf16) -> f32 ----------------
__global__ __launch_bounds__(256) void cvt_to_f32(const void* __restrict__ in,
                                                  float* __restrict__ out,
                                                  const uint* __restrict__ cosu,
                                                  int n)
{
    bool isbf = is_bf16_inputs(cosu);
    int i = blockIdx.x * 256 + threadIdx.x;
    if (i >= n) return;
    out[i] = isbf ? __bfloat162float(reinterpret_cast<const __hip_bfloat16*>(in)[i])
                  : reinterpret_cast<const float*>(in)[i];
}

// ---------------- transpose any (R x C) -> bf16 (C x R) ----------------
__global__ __launch_bounds__(256) void transpose_to_bf16(const void* __restrict__ in,
                                                         ushort* __restrict__ out,
                                                         int R, int C,
                                                         const uint* __restrict__ cosu)
{
    bool isbf = is_bf16_inputs(cosu);
    __shared__ ushort t[32][33];
    int bx = blockIdx.x * 32;
    int by = blockIdx.y * 32;
    int tx = threadIdx.x & 31, ty = threadIdx.x >> 5;
#pragma unroll
    for (int j = 0; j < 32; j += 8) {
        size_t idx = (size_t)(by + ty + j) * C + bx + tx;
        ushort v;
        if (isbf) v = reinterpret_cast<const ushort*>(in)[idx];
        else      v = f2bf(reinterpret_cast<const float*>(in)[idx]);
        t[ty + j][tx] = v;
    }
    __syncthreads();
#pragma unroll
    for (int j = 0; j < 32; j += 8)
        out[(size_t)(bx + ty + j) * R + by + tx] = t[tx][ty + j];
}

// ---------------- bf16 slab transpose: per-slab (R x C) -> (C x R) ----------------
__global__ __launch_bounds__(256) void transpose_slab_bf16(const ushort* __restrict__ in,
                                                           ushort* __restrict__ out,
                                                           int R, int C)
{
    __shared__ ushort t[32][33];
    const ushort* ip = in + (size_t)blockIdx.z * R * C;
    ushort* op = out + (size_t)blockIdx.z * R * C;
    int bx = blockIdx.x * 32, by = blockIdx.y * 32;
    int tx = threadIdx.x & 31, ty = threadIdx.x >> 5;
#pragma unroll
    for (int j = 0; j < 32; j += 8)
        t[ty + j][tx] = ip[(size_t)(by + ty + j) * C + bx + tx];
    __syncthreads();
#pragma unroll
    for (int j = 0; j < 32; j += 8)
        op[(size_t)(bx + ty + j) * R + by + tx] = t[tx][ty + j];
}

// ---------------- MFMA GEMM: C[M,N] = A[M,K] (bf16) x Bt[N,K]^T (bf16) ----------------
// A-frag: A[m=lane&15][k=quad*8+j]; B-frag: B[k=quad*8+j][n=lane&15] = Bt[n][k];
// C/D: row=quad*4+reg, col=lane&15.
template<int OUT_MODE>
__global__ __launch_bounds__(256) void gemm_bt(const ushort* __restrict__ A,
                                               const ushort* __restrict__ Bt,
                                               void* __restrict__ Cp,
                                               int M, int N, int K,
                                               const uint* __restrict__ cosu)
{
    __shared__ ushort lsA[64 * 72];
    __shared__ ushort lsB[64 * 72];
    const int tid = threadIdx.x;
    const int lane = tid & 63;
    const int wid = tid >> 6;
    const int wm = wid >> 1, wn = wid & 1;
    const int ln15 = lane & 15, quad = lane >> 4;
    const int rm = blockIdx.y * 64, cn = blockIdx.x * 64;

    const int srow = tid >> 2;
    const int sc8 = (tid & 3) * 2;

    floatx4 acc00 = {0,0,0,0}, acc01 = {0,0,0,0}, acc10 = {0,0,0,0}, acc11 = {0,0,0,0};

    for (int k0 = 0; k0 < K; k0 += 64) {
        __syncthreads();
        const uint4* ga = reinterpret_cast<const uint4*>(&A[(size_t)(rm + srow) * K + k0 + sc8 * 8]);
        uint4 va0 = ga[0], va1 = ga[1];
        const uint4* gb = reinterpret_cast<const uint4*>(&Bt[(size_t)(cn + srow) * K + k0 + sc8 * 8]);
        uint4 vb0 = gb[0], vb1 = gb[1];
        *reinterpret_cast<uint4*>(&lsA[srow * 72 + sc8 * 8]) = va0;
        *reinterpret_cast<uint4*>(&lsA[srow * 72 + sc8 * 8 + 8]) = va1;
        *reinterpret_cast<uint4*>(&lsB[srow * 72 + sc8 * 8]) = vb0;
        *reinterpret_cast<uint4*>(&lsB[srow * 72 + sc8 * 8 + 8]) = vb1;
        __syncthreads();
#pragma unroll
        for (int kk = 0; kk < 64; kk += 32) {
            short8 a0 = *reinterpret_cast<const short8*>(&lsA[(wm * 32 + ln15) * 72 + kk + quad * 8]);
            short8 a1 = *reinterpret_cast<const short8*>(&lsA[(wm * 32 + 16 + ln15) * 72 + kk + quad * 8]);
            short8 b0 = *reinterpret_cast<const short8*>(&lsB[(wn * 32 + ln15) * 72 + kk + quad * 8]);
            short8 b1 = *reinterpret_cast<const short8*>(&lsB[(wn * 32 + 16 + ln15) * 72 + kk + quad * 8]);
            acc00 = __builtin_amdgcn_mfma_f32_16x16x32_bf16(a0, b0, acc00, 0, 0, 0);
            acc01 = __builtin_amdgcn_mfma_f32_16x16x32_bf16(a0, b1, acc01, 0, 0, 0);
            acc10 = __builtin_amdgcn_mfma_f32_16x16x32_bf16(a1, b0, acc10, 0, 0, 0);
            acc11 = __builtin_amdgcn_mfma_f32_16x16x32_bf16(a1, b1, acc11, 0, 0, 0);
        }
    }

    bool outbf = (OUT_MODE == 1) ? is_bf16_inputs(cosu) : false;
#pragma unroll
    for (int mi = 0; mi < 2; ++mi) {
        floatx4 r0 = mi ? acc10 : acc00;
        floatx4 r1 = mi ? acc11 : acc01;
#pragma unroll
        for (int r = 0; r < 4; ++r) {
            int grow = rm + wm * 32 + mi * 16 + quad * 4 + r;
            int gc0 = cn + wn * 32 + ln15;
            if (OUT_MODE == 1 && outbf) {
                ushort* C = reinterpret_cast<ushort*>(Cp);
                C[(size_t)grow * N + gc0] = f2bf(r0[r]);
                C[(size_t)grow * N + gc0 + 16] = f2bf(r1[r]);
            } else {
                float* C = reinterpret_cast<float*>(Cp);
                C[(size_t)grow * N + gc0] = r0[r];
                C[(size_t)grow * N + gc0 + 16] = r1[r];
            }
        }
    }
}

// ---------------- L2 normalize + RoPE -> bf16 Q / K / V (all coalesced) ----------------
// qkv: fp32 [4096][1536]. Qb: bf16 [(b*16+h)*2048+s][64]; Kg: bf16 [(b*4+hkv)*2048+s][64];
// Vb: bf16 [(b*4+hkv)*2048+s][64]
__global__ __launch_bounds__(64) void norm_rope(const float* __restrict__ qkv,
                                                const float* __restrict__ cosf,
                                                const float* __restrict__ sinf,
                                                ushort* __restrict__ Qb,
                                                ushort* __restrict__ Kg,
                                                ushort* __restrict__ Vb)
{
    int lane = threadIdx.x;
    int hh = blockIdx.x % 24;
    int s = (blockIdx.x / 24) & (SLEN - 1);
    int b = blockIdx.x / (24 * SLEN);
    size_t row = (size_t)(b * SLEN + s) * 1536;

    if (hh >= 20) {
        int hkv = hh - 20;
        float v = qkv[row + 1280 + hkv * 64 + lane];
        Vb[((size_t)((b * NKV + hkv) * SLEN + s)) * 64 + lane] = f2bf(v);
        return;
    }
    bool isq = hh < 16;
    int col = isq ? hh * 64 : 1024 + (hh - 16) * 64;
    float v = qkv[row + col + lane];
    float ss = v * v;
#pragma unroll
    for (int off = 32; off; off >>= 1) ss += __shfl_xor(ss, off, 64);
    float nv = v / (sqrtf(ss) + 1e-8f);
    float p = __shfl(nv, lane ^ 32, 64);
    int dh = lane & 31;
    float c = cosf[s * 32 + dh];
    float sn = sinf[s * 32 + dh];
    float o = (lane < 32) ? (nv * c - p * sn) : (p * sn + nv * c);
    if (isq) {
        Qb[((size_t)((b * NHEADS + hh) * SLEN + s)) * 64 + lane] = f2bf(o);
    } else {
        int hkv = hh - 16;
        Kg[((size_t)((b * NKV + hkv) * SLEN + s)) * 64 + lane] = f2bf(o);
    }
}

// ---------------- MFMA windowed flash attention ----------------
// Block = 64 queries of one (b,h): 4 waves x 16 queries. Iterates 32-key chunks over
// [align32(q0-255), q0+63] plus a global chunk (keys 0..3) when that range excludes them.
// No running max needed: q,k unit vectors => |softcapped score| <= ~0.13, exp safe.
// Layouts match gemm_bt fragment mappings. P goes C-layout -> LDS -> A-frag (m120 pattern).
__global__ __launch_bounds__(256) void attn_mfma(const ushort* __restrict__ Qb,
                                                 const ushort* __restrict__ Kg,
                                                 const ushort* __restrict__ Vtg,
                                                 ushort* __restrict__ ctx)
{
    __shared__ ushort Ks[32 * 72];      // [32 keys][64 dims], stride 72
    __shared__ ushort Vs[64 * 40];      // [64 dims][32 keys], stride 40
    __shared__ ushort Ps[4][16 * 36];   // per-wave P: [16 q][32 k], stride 36

    const int tid = threadIdx.x;
    const int lane = tid & 63, w = tid >> 6;
    const int ln15 = lane & 15, quad = lane >> 4;
    const int bid = blockIdx.x;
    const int qt = bid & 31, bh = bid >> 5;
    const int h = bh & (NHEADS - 1), b = bh >> 4, hkv = h >> 2;
    const int q0 = qt * 64;
    const int qw = q0 + w * 16;

    const ushort* Qrow = Qb + ((size_t)bh * SLEN + qw) * 64;
    const ushort* Kbase = Kg + (size_t)(b * NKV + hkv) * SLEN * 64;
    const ushort* Vbase = Vtg + (size_t)(b * NKV + hkv) * 64 * SLEN;

    // Q fragments (A operand): lane m=ln15, k=quad*8+j (+32 for second half)
    short8 qf0 = *reinterpret_cast<const short8*>(Qrow + (size_t)ln15 * 64 + quad * 8);
    short8 qf1 = *reinterpret_cast<const short8*>(Qrow + (size_t)ln15 * 64 + 32 + quad * 8);

    floatx4 O0 = {0,0,0,0}, O1 = {0,0,0,0}, O2 = {0,0,0,0}, O3 = {0,0,0,0};
    float lp[4] = {0.f, 0.f, 0.f, 0.f};

    int kminA = q0 - (WINDOW - 1); if (kminA < 0) kminA = 0;
    kminA &= ~31;                              // 32-aligned staging start
    const int gmax = kminA < NGLOBAL ? kminA : NGLOBAL;  // globals below staged range
    const int nc = (q0 + 64 - kminA) >> 5;

    const int krow = tid >> 3, kcol = (tid & 7) * 8;   // K staging: 32 rows x 64 dims
    const int vrow = tid >> 2, vcol = (tid & 3) * 8;   // V staging: 64 rows x 32 keys

    for (int c = (gmax > 0 ? -1 : 0); c < nc; ++c) {
        const int kbase = (c < 0) ? 0 : kminA + c * 32;
        __syncthreads();
        *reinterpret_cast<uint4*>(&Ks[krow * 72 + kcol]) =
            *reinterpret_cast<const uint4*>(&Kbase[(size_t)(kbase + krow) * 64 + kcol]);
        *reinterpret_cast<uint4*>(&Vs[vrow * 40 + vcol]) =
            *reinterpret_cast<const uint4*>(&Vbase[(size_t)vrow * SLEN + kbase + vcol]);
        __syncthreads();

#pragma unroll
        for (int t = 0; t < 2; ++t) {
            short8 kf0 = *reinterpret_cast<const short8*>(&Ks[(t * 16 + ln15) * 72 + quad * 8]);
            short8 kf1 = *reinterpret_cast<const short8*>(&Ks[(t * 16 + ln15) * 72 + 32 + quad * 8]);
            floatx4 s = {0,0,0,0};
            s = __builtin_amdgcn_mfma_f32_16x16x32_bf16(qf0, kf0, s, 0, 0, 0);
            s = __builtin_amdgcn_mfma_f32_16x16x32_bf16(qf1, kf1, s, 0, 0, 0);
            const int k = kbase + t * 16 + ln15;
#pragma unroll
            for (int r = 0; r < 4; ++r) {
                const int q = qw + quad * 4 + r;
                const bool valid = (c < 0) ? (k < gmax)
                                           : (k <= q && (k + WINDOW > q || k < NGLOBAL));
                float sv = s[r] * 0.125f;                 // ATTN_SCALE
                float st = 15.f * tanhf(sv * (1.0f / 15.0f));
                ushort eb = valid ? f2bf(__expf(st)) : (ushort)0;
                Ps[w][(quad * 4 + r) * 36 + t * 16 + ln15] = eb;
                lp[r] += bf2f(eb);
            }
        }
        // P -> A-frag: lane m=ln15 reads keys quad*8..quad*8+7
        shortx4 plo = *reinterpret_cast<const shortx4*>(&Ps[w][ln15 * 36 + quad * 8]);
        shortx4 phi = *reinterpret_cast<const shortx4*>(&Ps[w][ln15 * 36 + quad * 8 + 4]);
        short8 af = __builtin_shufflevector(plo, phi, 0, 1, 2, 3, 4, 5, 6, 7);
        short8 vf0 = *reinterpret_cast<const short8*>(&Vs[(0 * 16 + ln15) * 40 + quad * 8]);
        short8 vf1 = *reinterpret_cast<const short8*>(&Vs[(1 * 16 + ln15) * 40 + quad * 8]);
        short8 vf2 = *reinterpret_cast<const short8*>(&Vs[(2 * 16 + ln15) * 40 + quad * 8]);
        short8 vf3 = *reinterpret_cast<const short8*>(&Vs[(3 * 16 + ln15) * 40 + quad * 8]);
        O0 = __builtin_amdgcn_mfma_f32_16x16x32_bf16(af, vf0, O0, 0, 0, 0);
        O1 = __builtin_amdgcn_mfma_f32_16x16x32_bf16(af, vf1, O1, 0, 0, 0);
        O2 = __builtin_amdgcn_mfma_f32_16x16x32_bf16(af, vf2, O2, 0, 0, 0);
        O3 = __builtin_amdgcn_mfma_f32_16x16x32_bf16(af, vf3, O3, 0, 0, 0);
    }

#pragma unroll
    for (int r = 0; r < 4; ++r) {
#pragma unroll
        for (int off = 1; off < 16; off <<= 1)
            lp[r] += __shfl_xor(lp[r], off, 64);
        const float inv = 1.f / lp[r];
        const int q = qw + quad * 4 + r;
        ushort* crow = ctx + ((size_t)(b * SLEN + q)) * DMODEL + h * 64 + ln15;
        crow[0]  = f2bf(O0[r] * inv);
        crow[16] = f2bf(O1[r] * inv);
        crow[32] = f2bf(O2[r] * inv);
        crow[48] = f2bf(O3[r] * inv);
    }
}

// ---------------- launch ----------------
extern "C" void kernel_launch(void* const* d_in, const int* in_sizes, int n_in,
                              void* d_out, int out_size, void* d_ws, size_t ws_size,
                              hipStream_t stream)
{
    (void)in_sizes; (void)n_in; (void)out_size; (void)ws_size;
    const void* x = d_in[0];
    const void* cosi = d_in[1];
    const void* sini = d_in[2];
    const uint* cosu = (const uint*)d_in[1];
    // d_in[3] = mask: computed analytically, not read
    const void* Wq = d_in[4];
    const void* Wk = d_in[5];
    const void* Wv = d_in[6];
    const void* Wo = d_in[7];

    // workspace layout
    ushort* xb = (ushort*)d_ws;                        // [4096][1024] bf16
    ushort* Wt = xb + (size_t)4096 * 1024;             // [1536][1024] bf16
    ushort* Wot = Wt + (size_t)1536 * 1024;            // [1024][1024] bf16
    float* cosf = (float*)(Wot + (size_t)1024 * 1024); // [2048*32] f32
    float* sinf = cosf + (size_t)SLEN * 32;
    float* qkv = sinf + (size_t)SLEN * 32;             // [4096][1536] f32
    ushort* Qbf = (ushort*)(qkv + (size_t)4096 * 1536);        // [2*16*2048][64]
    ushort* Kgf = Qbf + (size_t)BATCH * NHEADS * SLEN * 64;    // [2*4*2048][64]
    ushort* Vbf = Kgf + (size_t)BATCH * NKV * SLEN * 64;       // [2*4*2048][64]
    ushort* Vtg = Vbf + (size_t)BATCH * NKV * SLEN * 64;       // [2*4][64][2048]
    ushort* ctx = Vtg + (size_t)BATCH * NKV * 64 * SLEN;       // [4096][1024]

    // 0) canonicalize inputs
    cvt_to_bf16<<<dim3(2048), 256, 0, stream>>>(x, xb, cosu, (size_t)4096 * 1024 / 8);
    cvt_to_f32<<<dim3(256), 256, 0, stream>>>(cosi, cosf, cosu, SLEN * 32);
    cvt_to_f32<<<dim3(256), 256, 0, stream>>>(sini, sinf, cosu, SLEN * 32);

    // 1) transpose weights to K-major bf16
    transpose_to_bf16<<<dim3(32, 32), 256, 0, stream>>>(Wq, Wt, 1024, 1024, cosu);
    transpose_to_bf16<<<dim3(8, 32), 256, 0, stream>>>(Wk, Wt + (size_t)1024 * 1024, 1024, 256, cosu);
    transpose_to_bf16<<<dim3(8, 32), 256, 0, stream>>>(Wv, Wt + (size_t)1280 * 1024, 1024, 256, cosu);
    transpose_to_bf16<<<dim3(32, 32), 256, 0, stream>>>(Wo, Wot, 1024, 1024, cosu);

    // 2) fused QKV projection -> f32
    gemm_bt<0><<<dim3(24, 64), 256, 0, stream>>>(xb, Wt, qkv, 4096, 1536, 1024, cosu);

    // 3) l2-normalize + rope -> bf16 Q/K/V
    norm_rope<<<dim3(BATCH * SLEN * 24), 64, 0, stream>>>(qkv, cosf, sinf, Qbf, Kgf, Vbf);

    // 4) V -> V^T per (b,hkv) slab
    transpose_slab_bf16<<<dim3(2, 64, BATCH * NKV), 256, 0, stream>>>(Vbf, Vtg, SLEN, 64);

    // 5) MFMA windowed attention
    attn_mfma<<<dim3(BATCH * NHEADS * SLEN / 64), 256, 0, stream>>>(Qbf, Kgf, Vtg, ctx);

    // 6) output projection -> d_out (dtype-matched)
    gemm_bt<1><<<dim3(16, 64), 256, 0, stream>>>(ctx, Wot, d_out, 4096, 1024, 1024, cosu);
}

// Round 4
// 192.495 us; speedup vs baseline: 4.3912x; 1.0601x over previous
//
#include <hip/hip_runtime.h>
#include <hip/hip_bf16.h>

// Problem constants
#define BATCH 2
#define SLEN 2048
#define DMODEL 1024
#define NHEADS 16
#define NKV 4
#define DHEAD 64
#define WINDOW 256
#define NGLOBAL 4

typedef __attribute__((ext_vector_type(8))) short short8;
typedef __attribute__((ext_vector_type(4))) float floatx4;

__device__ __forceinline__ ushort f2bf(float f) {
    __hip_bfloat16 h = __float2bfloat16(f);
    return *reinterpret_cast<ushort*>(&h);
}
__device__ __forceinline__ float bf2f(ushort u) {
    __hip_bfloat16 h = *reinterpret_cast<__hip_bfloat16*>(&u);
    return __bfloat162float(h);
}
// dtype flag: cos[0]==1.0f exactly. fp32 -> low16 of first dword == 0x0000;
// bf16 pair -> low16 == 0x3F80. Wave-uniform branch, graph-capture safe.
__device__ __forceinline__ bool is_bf16_inputs(const uint* cosu) {
    return (cosu[0] & 0xFFFFu) != 0u;
}
// async global->LDS, 16B per lane. LDS dest is wave-uniform base + lane*16.
__device__ __forceinline__ void gload_lds16(const ushort* g, ushort* l) {
    __builtin_amdgcn_global_load_lds(
        (const __attribute__((address_space(1))) void*)g,
        (__attribute__((address_space(3))) void*)l, 16, 0, 0);
}

// ---------------- fused input canonicalization ----------------
// y==0: x -> bf16 (vectorized x8). y==1: cos|sin -> f32.
__global__ __launch_bounds__(256) void cvt_inputs(const void* __restrict__ x,
                                                  const void* __restrict__ cosi,
                                                  const void* __restrict__ sini,
                                                  ushort* __restrict__ xb,
                                                  float* __restrict__ cosf,
                                                  float* __restrict__ sinf,
                                                  const uint* __restrict__ cosu)
{
    const bool isbf = is_bf16_inputs(cosu);
    if (blockIdx.y == 0) {
        size_t i = (size_t)blockIdx.x * 256 + threadIdx.x;   // 8-elem chunk, 524288 total
        size_t e = i * 8;
        if (isbf) {
            *reinterpret_cast<uint4*>(xb + e) = reinterpret_cast<const uint4*>(x)[i];
        } else {
            const float* f = reinterpret_cast<const float*>(x) + e;
            ushort o[8];
#pragma unroll
            for (int j = 0; j < 8; ++j) o[j] = f2bf(f[j]);
            *reinterpret_cast<uint4*>(xb + e) = *reinterpret_cast<uint4*>(o);
        }
    } else {
        int i = blockIdx.x * 256 + threadIdx.x;
        if (i >= 2 * SLEN * 32) return;
        const void* src = (i < SLEN * 32) ? cosi : sini;
        float* dst = (i < SLEN * 32) ? cosf : sinf;
        int e = i & (SLEN * 32 - 1);
        dst[e] = isbf ? bf2f(reinterpret_cast<const ushort*>(src)[e])
                      : reinterpret_cast<const float*>(src)[e];
    }
}

// ---------------- fused weight transpose: all 4 weights -> K-major bf16 ----------------
__global__ __launch_bounds__(256) void prep_weights(const void* __restrict__ Wq,
                                                    const void* __restrict__ Wk,
                                                    const void* __restrict__ Wv,
                                                    const void* __restrict__ Wo,
                                                    ushort* __restrict__ Wt,
                                                    ushort* __restrict__ Wot,
                                                    const uint* __restrict__ cosu)
{
    const bool isbf = is_bf16_inputs(cosu);
    const int z = blockIdx.z;
    const void* src; ushort* dst; int C;
    if (z == 0)      { src = Wq; dst = Wt;                        C = 1024; }
    else if (z == 1) { src = Wk; dst = Wt + (size_t)1024 * 1024;  C = 256; }
    else if (z == 2) { src = Wv; dst = Wt + (size_t)1280 * 1024;  C = 256; }
    else             { src = Wo; dst = Wot;                       C = 1024; }
    const int bx = blockIdx.x * 32;
    if (bx >= C) return;
    const int by = blockIdx.y * 32;
    __shared__ ushort t[32][33];
    const int tx = threadIdx.x & 31, ty = threadIdx.x >> 5;
#pragma unroll
    for (int j = 0; j < 32; j += 8) {
        size_t idx = (size_t)(by + ty + j) * C + bx + tx;
        t[ty + j][tx] = isbf ? reinterpret_cast<const ushort*>(src)[idx]
                             : f2bf(reinterpret_cast<const float*>(src)[idx]);
    }
    __syncthreads();
#pragma unroll
    for (int j = 0; j < 32; j += 8)
        dst[(size_t)(bx + ty + j) * 1024 + by + tx] = t[tx][ty + j];
}

// ---------------- bf16 slab transpose: per-slab (R x C) -> (C x R) ----------------
__global__ __launch_bounds__(256) void transpose_slab_bf16(const ushort* __restrict__ in,
                                                           ushort* __restrict__ out,
                                                           int R, int C)
{
    __shared__ ushort t[32][33];
    const ushort* ip = in + (size_t)blockIdx.z * R * C;
    ushort* op = out + (size_t)blockIdx.z * R * C;
    int bx = blockIdx.x * 32, by = blockIdx.y * 32;
    int tx = threadIdx.x & 31, ty = threadIdx.x >> 5;
#pragma unroll
    for (int j = 0; j < 32; j += 8)
        t[ty + j][tx] = ip[(size_t)(by + ty + j) * C + bx + tx];
    __syncthreads();
#pragma unroll
    for (int j = 0; j < 32; j += 8)
        op[(size_t)(bx + ty + j) * R + by + tx] = t[tx][ty + j];
}

// ---------------- m97-style MFMA GEMM: C[M,N] = A[M,K] x Bt[N,K]^T (bf16) ----------------
// 128x128 tile, BK=64, 4 waves 2x2, each wave 64x64 = 4x4 fragments of 16x16x32.
// Staging via global_load_lds width=16, LDS unpadded [128][64] (m97 structure, 874 TF).
// A-frag: A[m=lane&15][k=quad*8+j]; B-frag: Bt[n=lane&15][k]; C/D: row=quad*4+reg, col=lane&15.
// OUT_MODE: 1 = dynamic (bf16 if inputs bf16 else f32), 2 = always bf16.
template<int OUT_MODE>
__global__ __launch_bounds__(256) void gemm128(const ushort* __restrict__ A,
                                               const ushort* __restrict__ Bt,
                                               void* __restrict__ Cp,
                                               int M, int N, int K,
                                               const uint* __restrict__ cosu)
{
    __shared__ ushort lsA[128 * 64];
    __shared__ ushort lsB[128 * 64];
    const int tid = threadIdx.x;
    const int lane = tid & 63, w = tid >> 6;
    const int ln15 = lane & 15, quad = lane >> 4;
    const int wm = w >> 1, wn = w & 1;
    const int rm = blockIdx.y * 128, cn = blockIdx.x * 128;

    floatx4 acc[4][4];
#pragma unroll
    for (int i = 0; i < 4; ++i)
#pragma unroll
        for (int j = 0; j < 4; ++j) acc[i][j] = (floatx4){0.f, 0.f, 0.f, 0.f};

    for (int k0 = 0; k0 < K; k0 += 64) {
        __syncthreads();
#pragma unroll
        for (int i = 0; i < 4; ++i) {
            const int c = (i * 4 + w) * 64 + lane;       // chunk id 0..1023
            const int row = c >> 3, col = (c & 7) * 8;   // [128 rows][64 cols]
            gload_lds16(&A[(size_t)(rm + row) * K + k0 + col], &lsA[(i * 4 + w) * 512]);
            gload_lds16(&Bt[(size_t)(cn + row) * K + k0 + col], &lsB[(i * 4 + w) * 512]);
        }
        __syncthreads();
#pragma unroll
        for (int kk = 0; kk < 64; kk += 32) {
            short8 af[4], bf[4];
#pragma unroll
            for (int i = 0; i < 4; ++i) {
                af[i] = *reinterpret_cast<const short8*>(&lsA[(wm * 64 + i * 16 + ln15) * 64 + kk + quad * 8]);
                bf[i] = *reinterpret_cast<const short8*>(&lsB[(wn * 64 + i * 16 + ln15) * 64 + kk + quad * 8]);
            }
#pragma unroll
            for (int i = 0; i < 4; ++i)
#pragma unroll
                for (int j = 0; j < 4; ++j)
                    acc[i][j] = __builtin_amdgcn_mfma_f32_16x16x32_bf16(af[i], bf[j], acc[i][j], 0, 0, 0);
        }
    }

    const bool outbf = (OUT_MODE == 2) || is_bf16_inputs(cosu);
#pragma unroll
    for (int i = 0; i < 4; ++i) {
#pragma unroll
        for (int r = 0; r < 4; ++r) {
            const int grow = rm + wm * 64 + i * 16 + quad * 4 + r;
#pragma unroll
            for (int j = 0; j < 4; ++j) {
                const int gcol = cn + wn * 64 + j * 16 + ln15;
                if (outbf) reinterpret_cast<ushort*>(Cp)[(size_t)grow * N + gcol] = f2bf(acc[i][j][r]);
                else       reinterpret_cast<float*>(Cp)[(size_t)grow * N + gcol] = acc[i][j][r];
            }
        }
    }
}

// ---------------- L2 normalize + RoPE -> bf16 Q / K / V ----------------
// qkvb: bf16 [4096][1536]. One wave per (b,s,head-slot); 4 waves/block.
__global__ __launch_bounds__(256) void norm_rope(const ushort* __restrict__ qkvb,
                                                 const float* __restrict__ cosf,
                                                 const float* __restrict__ sinf,
                                                 ushort* __restrict__ Qb,
                                                 ushort* __restrict__ Kg,
                                                 ushort* __restrict__ Vb)
{
    const int lane = threadIdx.x & 63;
    const int g = blockIdx.x * 4 + (threadIdx.x >> 6);
    const int hh = g % 24;                    // 0..15 q, 16..19 k, 20..23 v
    const int s = (g / 24) & (SLEN - 1);
    const int b = g / (24 * SLEN);
    const size_t row = (size_t)(b * SLEN + s) * 1536;

    if (hh >= 20) {
        int hkv = hh - 20;
        Vb[((size_t)((b * NKV + hkv) * SLEN + s)) * 64 + lane] = qkvb[row + 1280 + hkv * 64 + lane];
        return;
    }
    const bool isq = hh < 16;
    const int col = isq ? hh * 64 : 1024 + (hh - 16) * 64;
    float v = bf2f(qkvb[row + col + lane]);
    float ss = v * v;
#pragma unroll
    for (int off = 32; off; off >>= 1) ss += __shfl_xor(ss, off, 64);
    float nv = v / (sqrtf(ss) + 1e-8f);
    float p = __shfl(nv, lane ^ 32, 64);
    int dh = lane & 31;
    float c = cosf[s * 32 + dh];
    float sn = sinf[s * 32 + dh];
    float o = (lane < 32) ? (nv * c - p * sn) : (p * sn + nv * c);
    if (isq) Qb[((size_t)((b * NHEADS + hh) * SLEN + s)) * 64 + lane] = f2bf(o);
    else {
        int hkv = hh - 16;
        Kg[((size_t)((b * NKV + hkv) * SLEN + s)) * 64 + lane] = f2bf(o);
    }
}

// ---------------- MFMA windowed flash attention, 64-key chunks ----------------
// Block = 64 queries of one (b,h): 4 waves x 16 q. Chunks of 64 keys over
// [align64(q0-255), q0+63] plus one global chunk (keys 0..3) when excluded.
// No running max: q,k unit vectors => |score*scale| <= 0.125, exp safe.
// softcap-exp: st = 15 - 30/(e^{2*sv/15}+1); p = exp(st). (|tanh arg| <= 0.0083)
__global__ __launch_bounds__(256) void attn_mfma(const ushort* __restrict__ Qb,
                                                 const ushort* __restrict__ Kg,
                                                 const ushort* __restrict__ Vtg,
                                                 ushort* __restrict__ ctx)
{
    __shared__ ushort Ks[64 * 72];      // [64 keys][64 dims], stride 72
    __shared__ ushort Vs[64 * 72];      // [64 dims][64 keys], stride 72
    __shared__ ushort Ps[4][16 * 72];   // per-wave P: [16 q][64 k], stride 72

    const int tid = threadIdx.x;
    const int lane = tid & 63, w = tid >> 6;
    const int ln15 = lane & 15, quad = lane >> 4;
    const int bid = blockIdx.x;
    const int qt = bid & 31, bh = bid >> 5;
    const int h = bh & (NHEADS - 1), b = bh >> 4, hkv = h >> 2;
    const int q0 = qt * 64;
    const int qw = q0 + w * 16;

    const ushort* Qrow = Qb + ((size_t)bh * SLEN + qw) * 64;
    const ushort* Kbase = Kg + (size_t)(b * NKV + hkv) * SLEN * 64;
    const ushort* Vbase = Vtg + (size_t)(b * NKV + hkv) * 64 * SLEN;

    short8 qf0 = *reinterpret_cast<const short8*>(Qrow + (size_t)ln15 * 64 + quad * 8);
    short8 qf1 = *reinterpret_cast<const short8*>(Qrow + (size_t)ln15 * 64 + 32 + quad * 8);

    floatx4 O0 = {0,0,0,0}, O1 = {0,0,0,0}, O2 = {0,0,0,0}, O3 = {0,0,0,0};
    float lp[4] = {0.f, 0.f, 0.f, 0.f};

    int kminA = q0 - (WINDOW - 1); if (kminA < 0) kminA = 0;
    kminA &= ~63;
    const int gmax = kminA < NGLOBAL ? kminA : NGLOBAL;
    const int nc = (q0 + 64 - kminA) >> 6;

    for (int c = (gmax > 0 ? -1 : 0); c < nc; ++c) {
        const int kbase = (c < 0) ? 0 : kminA + c * 64;
        __syncthreads();
#pragma unroll
        for (int j = 0; j < 2; ++j) {
            const int c2 = tid + j * 256;                 // chunk 0..511
            const int row = c2 >> 3, col = (c2 & 7) * 8;
            *reinterpret_cast<uint4*>(&Ks[row * 72 + col]) =
                *reinterpret_cast<const uint4*>(&Kbase[(size_t)(kbase + row) * 64 + col]);
            *reinterpret_cast<uint4*>(&Vs[row * 72 + col]) =
                *reinterpret_cast<const uint4*>(&Vbase[(size_t)row * SLEN + kbase + col]);
        }
        __syncthreads();

#pragma unroll
        for (int t = 0; t < 4; ++t) {
            short8 kf0 = *reinterpret_cast<const short8*>(&Ks[(t * 16 + ln15) * 72 + quad * 8]);
            short8 kf1 = *reinterpret_cast<const short8*>(&Ks[(t * 16 + ln15) * 72 + 32 + quad * 8]);
            floatx4 sc = {0,0,0,0};
            sc = __builtin_amdgcn_mfma_f32_16x16x32_bf16(qf0, kf0, sc, 0, 0, 0);
            sc = __builtin_amdgcn_mfma_f32_16x16x32_bf16(qf1, kf1, sc, 0, 0, 0);
            const int k = kbase + t * 16 + ln15;
#pragma unroll
            for (int r = 0; r < 4; ++r) {
                const int q = qw + quad * 4 + r;
                const bool valid = (c < 0) ? (k < gmax)
                                           : (k <= q && (k + WINDOW > q || k < NGLOBAL));
                float sv = sc[r] * 0.125f;                     // ATTN_SCALE
                float e2 = __expf(sv * 0.13333333f);           // e^{2*sv/15}
                float st = 15.f - 30.f * __builtin_amdgcn_rcpf(e2 + 1.f);
                ushort eb = valid ? f2bf(__expf(st)) : (ushort)0;
                Ps[w][(quad * 4 + r) * 72 + t * 16 + ln15] = eb;
                lp[r] += bf2f(eb);
            }
        }
        // P -> A-frag (in-wave LDS round trip; DS ops are in-order per wave)
        short8 af0 = *reinterpret_cast<const short8*>(&Ps[w][ln15 * 72 + quad * 8]);
        short8 af1 = *reinterpret_cast<const short8*>(&Ps[w][ln15 * 72 + 32 + quad * 8]);
#pragma unroll
        for (int n = 0; n < 4; ++n) {
            short8 vf0 = *reinterpret_cast<const short8*>(&Vs[(n * 16 + ln15) * 72 + quad * 8]);
            short8 vf1 = *reinterpret_cast<const short8*>(&Vs[(n * 16 + ln15) * 72 + 32 + quad * 8]);
            floatx4 On = (n == 0) ? O0 : (n == 1) ? O1 : (n == 2) ? O2 : O3;
            On = __builtin_amdgcn_mfma_f32_16x16x32_bf16(af0, vf0, On, 0, 0, 0);
            On = __builtin_amdgcn_mfma_f32_16x16x32_bf16(af1, vf1, On, 0, 0, 0);
            if (n == 0) O0 = On; else if (n == 1) O1 = On; else if (n == 2) O2 = On; else O3 = On;
        }
    }

#pragma unroll
    for (int r = 0; r < 4; ++r) {
#pragma unroll
        for (int off = 1; off < 16; off <<= 1)
            lp[r] += __shfl_xor(lp[r], off, 64);
        const float inv = __builtin_amdgcn_rcpf(lp[r]);
        const int q = qw + quad * 4 + r;
        ushort* crow = ctx + ((size_t)(b * SLEN + q)) * DMODEL + h * 64 + ln15;
        crow[0]  = f2bf(O0[r] * inv);
        crow[16] = f2bf(O1[r] * inv);
        crow[32] = f2bf(O2[r] * inv);
        crow[48] = f2bf(O3[r] * inv);
    }
}

// ---------------- launch ----------------
extern "C" void kernel_launch(void* const* d_in, const int* in_sizes, int n_in,
                              void* d_out, int out_size, void* d_ws, size_t ws_size,
                              hipStream_t stream)
{
    (void)in_sizes; (void)n_in; (void)out_size; (void)ws_size;
    const void* x = d_in[0];
    const void* cosi = d_in[1];
    const void* sini = d_in[2];
    const uint* cosu = (const uint*)d_in[1];
    // d_in[3] = mask: computed analytically, not read
    const void* Wq = d_in[4];
    const void* Wk = d_in[5];
    const void* Wv = d_in[6];
    const void* Wo = d_in[7];

    // workspace layout (~48 MB)
    ushort* xb = (ushort*)d_ws;                        // [4096][1024] bf16
    ushort* Wt = xb + (size_t)4096 * 1024;             // [1536][1024] bf16
    ushort* Wot = Wt + (size_t)1536 * 1024;            // [1024][1024] bf16
    float* cosf = (float*)(Wot + (size_t)1024 * 1024); // [2048*32] f32
    float* sinf = cosf + (size_t)SLEN * 32;
    ushort* qkvb = (ushort*)(sinf + (size_t)SLEN * 32);        // [4096][1536] bf16
    ushort* Qbf = qkvb + (size_t)4096 * 1536;                  // [2*16*2048][64]
    ushort* Kgf = Qbf + (size_t)BATCH * NHEADS * SLEN * 64;    // [2*4*2048][64]
    ushort* Vbf = Kgf + (size_t)BATCH * NKV * SLEN * 64;       // [2*4*2048][64]
    ushort* Vtg = Vbf + (size_t)BATCH * NKV * SLEN * 64;       // [2*4][64][2048]
    ushort* ctx = Vtg + (size_t)BATCH * NKV * 64 * SLEN;       // [4096][1024]

    // 0) canonicalize inputs (x->bf16, cos/sin->f32), dtype from cos[0]
    cvt_inputs<<<dim3(2048, 2), 256, 0, stream>>>(x, cosi, sini, xb, cosf, sinf, cosu);

    // 1) all weight transposes in one dispatch
    prep_weights<<<dim3(32, 32, 4), 256, 0, stream>>>(Wq, Wk, Wv, Wo, Wt, Wot, cosu);

    // 2) fused QKV projection -> bf16 [4096][1536]
    gemm128<2><<<dim3(12, 32), 256, 0, stream>>>(xb, Wt, qkvb, 4096, 1536, 1024, cosu);

    // 3) l2-normalize + rope -> bf16 Q/K/V
    norm_rope<<<dim3(BATCH * SLEN * 24 / 4), 256, 0, stream>>>(qkvb, cosf, sinf, Qbf, Kgf, Vbf);

    // 4) V -> V^T per (b,hkv) slab
    transpose_slab_bf16<<<dim3(2, 64, BATCH * NKV), 256, 0, stream>>>(Vbf, Vtg, SLEN, 64);

    // 5) MFMA windowed attention
    attn_mfma<<<dim3(BATCH * NHEADS * SLEN / 64), 256, 0, stream>>>(Qbf, Kgf, Vtg, ctx);

    // 6) output projection -> d_out (dtype-matched)
    gemm128<1><<<dim3(8, 32), 256, 0, stream>>>(ctx, Wot, d_out, 4096, 1024, 1024, cosu);
}